// Round 7
// baseline (1106.562 us; speedup 1.0000x reference)
//
#include <hip/hip_runtime.h>
#include <hip/hip_bf16.h>
#include <cstddef>
#include <cstdint>

#define D_MODEL 1024
#define D_STATE 16
#define D_CONV  4
#define D_INNER 2048
#define DT_RANK 64
#define BATCH   4
#define SEQLEN  2048
#define NTOK    (BATCH * SEQLEN)   // 8192 rows

#define SCAN_CH 32                 // time chunks
#define SCAN_CL 64                 // steps per chunk (SCAN_CH*SCAN_CL == SEQLEN)

typedef unsigned short u16;
typedef __attribute__((ext_vector_type(4))) unsigned short u16x4;
typedef __attribute__((ext_vector_type(8))) short bf16x8;   // 8 bf16 in 4 VGPRs
typedef __attribute__((ext_vector_type(4))) float f32x4;

// bf16 round-to-nearest-even (finite inputs)
__device__ __forceinline__ u16 bf16r(float f) {
    union { float f; uint32_t u; } v; v.f = f;
    uint32_t r = v.u + 0x7FFF + ((v.u >> 16) & 1);
    return (u16)(r >> 16);
}
__device__ __forceinline__ float b2f(u16 u) {
    union { uint32_t u; float f; } v; v.u = ((uint32_t)u) << 16;
    return v.f;
}

// async global->LDS, 16B per lane. LDS base must be wave-uniform; HW scatters lane*16.
__device__ __forceinline__ void gload16(const void* g, void* l) {
    __builtin_amdgcn_global_load_lds(
        (const __attribute__((address_space(1))) uint32_t*)g,
        (__attribute__((address_space(3))) uint32_t*)l, 16, 0, 0);
}

// ---------------------------------------------------------------------------
// Weight transpose + cast: src fp32 [Ksrc][Nsrc] -> dst bf16 [Npad][Ksrc],
// rows n >= Nsrc zero-filled. grid = (Ksrc/64, Npad/64), block 256.
// ---------------------------------------------------------------------------
__global__ __launch_bounds__(256) void transpose_w_kernel(
    const float* __restrict__ src, int Ksrc, int Nsrc, u16* __restrict__ dst)
{
    __shared__ float t[64][65];
    int k0 = blockIdx.x * 64, n0 = blockIdx.y * 64;
    int tid = threadIdx.x;
    #pragma unroll
    for (int i = 0; i < 16; ++i) {
        int idx = tid + i * 256;
        int r = idx >> 6, c = idx & 63;
        float v = 0.0f;
        if (n0 + c < Nsrc) v = src[(size_t)(k0 + r) * Nsrc + (n0 + c)];
        t[r][c] = v;
    }
    __syncthreads();
    #pragma unroll
    for (int i = 0; i < 16; ++i) {
        int idx = tid + i * 256;
        int r = idx >> 6, c = idx & 63;
        dst[(size_t)(n0 + r) * Ksrc + (k0 + c)] = bf16r(t[c][r]);
    }
}

// ---------------------------------------------------------------------------
// RMSNorm: one block per row (1024 floats) -> bf16 out
// ---------------------------------------------------------------------------
__global__ __launch_bounds__(256) void rmsnorm_kernel(
    const float* __restrict__ x, const float* __restrict__ w, u16* __restrict__ o)
{
    int row = blockIdx.x;
    const float* xr = x + (size_t)row * D_MODEL;
    float4 v = *reinterpret_cast<const float4*>(xr + threadIdx.x * 4);
    float ss = v.x * v.x + v.y * v.y + v.z * v.z + v.w * v.w;
    #pragma unroll
    for (int off = 32; off > 0; off >>= 1) ss += __shfl_down(ss, off);
    __shared__ float sred[4];
    if ((threadIdx.x & 63) == 0) sred[threadIdx.x >> 6] = ss;
    __syncthreads();
    float tot = sred[0] + sred[1] + sred[2] + sred[3];
    float scale = rsqrtf(tot * (1.0f / D_MODEL) + 1e-6f);
    float4 wv = *reinterpret_cast<const float4*>(w + threadIdx.x * 4);
    u16x4 ov;
    ov[0] = bf16r(v.x * scale * wv.x); ov[1] = bf16r(v.y * scale * wv.y);
    ov[2] = bf16r(v.z * scale * wv.z); ov[3] = bf16r(v.w * scale * wv.w);
    *reinterpret_cast<u16x4*>(o + (size_t)row * D_MODEL + threadIdx.x * 4) = ov;
}

// ---------------------------------------------------------------------------
// LayerNorm: one block per row -> bf16 out
// ---------------------------------------------------------------------------
__global__ __launch_bounds__(256) void layernorm_kernel(
    const float* __restrict__ x, const float* __restrict__ w, const float* __restrict__ b,
    u16* __restrict__ o)
{
    int row = blockIdx.x;
    const float* xr = x + (size_t)row * D_MODEL;
    float4 v = *reinterpret_cast<const float4*>(xr + threadIdx.x * 4);
    float s1 = v.x + v.y + v.z + v.w;
    float s2 = v.x * v.x + v.y * v.y + v.z * v.z + v.w * v.w;
    #pragma unroll
    for (int off = 32; off > 0; off >>= 1) {
        s1 += __shfl_down(s1, off);
        s2 += __shfl_down(s2, off);
    }
    __shared__ float r1[4], r2[4];
    if ((threadIdx.x & 63) == 0) { r1[threadIdx.x >> 6] = s1; r2[threadIdx.x >> 6] = s2; }
    __syncthreads();
    float t1 = r1[0] + r1[1] + r1[2] + r1[3];
    float t2 = r2[0] + r2[1] + r2[2] + r2[3];
    float mu = t1 * (1.0f / D_MODEL);
    float var = t2 * (1.0f / D_MODEL) - mu * mu;
    float inv = rsqrtf(var + 1e-5f);
    float4 wv = *reinterpret_cast<const float4*>(w + threadIdx.x * 4);
    float4 bv = *reinterpret_cast<const float4*>(b + threadIdx.x * 4);
    u16x4 ov;
    ov[0] = bf16r((v.x - mu) * inv * wv.x + bv.x);
    ov[1] = bf16r((v.y - mu) * inv * wv.y + bv.y);
    ov[2] = bf16r((v.z - mu) * inv * wv.z + bv.z);
    ov[3] = bf16r((v.w - mu) * inv * wv.w + bv.w);
    *reinterpret_cast<u16x4*>(o + (size_t)row * D_MODEL + threadIdx.x * 4) = ov;
}

// ---------------------------------------------------------------------------
// bf16 MFMA GEMM (m97 structure): C[M,N] = epi(A[M,K]bf16 @ B[K,N]), B given
// as B^T bf16 [N][ldb]. 128x128 tile, BK=32, 256 threads = 4 waves (2x2),
// each wave 64x64 via 4x4 x mfma_f32_16x16x32_bf16, fp32 accumulate.
// EPI: 0 C=f32 | 1 C2=bf16 | 2 C=f32 + C2=bf16 | 3 softplus(t+bias)->f32
//      4 t+res->f32 | 5 t+bias->bf16 | 6 t+bias+res->f32
// ---------------------------------------------------------------------------
template<int EPI>
__global__ __launch_bounds__(256) void gemm_bf16(
    const u16* __restrict__ A, int lda,
    const u16* __restrict__ Bt, int ldb,
    int K, int Nreal,
    float* __restrict__ C, int ldc,
    u16* __restrict__ C2, int ldc2,
    const float* __restrict__ bias,
    const float* __restrict__ res, int ldres)
{
    __shared__ u16 As[128 * 32];   // [row][k] 64B rows
    __shared__ u16 Bs[128 * 32];   // [ncol][k]
    const int tid = threadIdx.x;
    const int l = tid & 63;
    const int w = tid >> 6;
    const int wm = w >> 1, wn = w & 1;
    const int bm = blockIdx.y * 128, bn = blockIdx.x * 128;

    f32x4 acc[4][4] = {};

    const char* Ab = (const char*)A + (size_t)bm * lda * 2;
    const char* Bb = (const char*)Bt + (size_t)bn * ldb * 2;
    const int o0 = tid * 16;
    const int row0 = o0 >> 6, col0 = o0 & 63;   // tile row / byte-in-row for staging
    u16* AsW = As + (w << 9);                   // wave-uniform LDS base (1024 B/wave)
    u16* BsW = Bs + (w << 9);

    for (int k0 = 0; k0 < K; k0 += 32) {
        const int kb = k0 * 2;
        gload16(Ab + (size_t)row0 * (lda * 2) + kb + col0, AsW);
        gload16(Ab + (size_t)(row0 + 64) * (lda * 2) + kb + col0, AsW + 2048);
        gload16(Bb + (size_t)row0 * (ldb * 2) + kb + col0, BsW);
        gload16(Bb + (size_t)(row0 + 64) * (ldb * 2) + kb + col0, BsW + 2048);
        __syncthreads();   // drains vmcnt: LDS tiles ready

        const int half16 = (l >> 4) << 4;   // k-half byte offset
        bf16x8 af[4], bfr[4];
        #pragma unroll
        for (int m = 0; m < 4; ++m) {
            int r = wm * 64 + m * 16 + (l & 15);
            af[m] = *reinterpret_cast<const bf16x8*>((const char*)As + r * 64 + half16);
        }
        #pragma unroll
        for (int n = 0; n < 4; ++n) {
            int r = wn * 64 + n * 16 + (l & 15);
            bfr[n] = *reinterpret_cast<const bf16x8*>((const char*)Bs + r * 64 + half16);
        }
        #pragma unroll
        for (int m = 0; m < 4; ++m)
            #pragma unroll
            for (int n = 0; n < 4; ++n)
                acc[m][n] = __builtin_amdgcn_mfma_f32_16x16x32_bf16(
                    af[m], bfr[n], acc[m][n], 0, 0, 0);
        __syncthreads();   // all reads done before next stage overwrites
    }

    const int cr0 = (l >> 4) * 4;
    const int cc = l & 15;
    #pragma unroll
    for (int m = 0; m < 4; ++m) {
        #pragma unroll
        for (int n = 0; n < 4; ++n) {
            #pragma unroll
            for (int r = 0; r < 4; ++r) {
                int row = bm + wm * 64 + m * 16 + cr0 + r;
                int col = bn + wn * 64 + n * 16 + cc;
                if (col >= Nreal) continue;
                float t = acc[m][n][r];
                if (EPI == 3 || EPI == 5 || EPI == 6) t += bias[col];
                if (EPI == 3) t = (t > 20.0f) ? t : log1pf(__expf(t));
                if (EPI == 4 || EPI == 6) t += res[(size_t)row * ldres + col];
                if (EPI == 0 || EPI == 2 || EPI == 3 || EPI == 4 || EPI == 6)
                    C[(size_t)row * ldc + col] = t;
                if (EPI == 1 || EPI == 2 || EPI == 5)
                    C2[(size_t)row * ldc2 + col] = bf16r(t);
            }
        }
    }
}

// ---------------------------------------------------------------------------
// Depthwise causal conv (width 4) + bias + SiLU. fp32 in -> bf16 out.
// ---------------------------------------------------------------------------
__global__ __launch_bounds__(256) void conv_silu_kernel(
    const float* __restrict__ xr, const float* __restrict__ cw,
    const float* __restrict__ cb, u16* __restrict__ xi)
{
    int idx = blockIdx.x * 256 + threadIdx.x;
    if (idx >= NTOK * D_INNER) return;
    int d = idx & (D_INNER - 1);
    int bt = idx >> 11;
    int t = bt & (SEQLEN - 1);
    const float* base = xr + (size_t)bt * D_INNER + d;
    float w0 = cw[d * 4 + 0], w1 = cw[d * 4 + 1], w2 = cw[d * 4 + 2], w3 = cw[d * 4 + 3];
    float acc = cb[d] + w3 * base[0];
    if (t >= 1) acc += w2 * base[-(ptrdiff_t)D_INNER];
    if (t >= 2) acc += w1 * base[-(ptrdiff_t)(2 * D_INNER)];
    if (t >= 3) acc += w0 * base[-(ptrdiff_t)(3 * D_INNER)];
    float s = acc / (1.0f + __expf(-acc));
    xi[idx] = bf16r(s);
}

// ---------------------------------------------------------------------------
// Chunked selective scan (3 phases). h_t = dA_t*h_{t-1} + (dt*x)_t*B_t.
// Summary layout: sum[(((b*CH + c)*32 + slot)*D_INNER) + d], slot 0..15 = P
// (per-chunk decay product), 16..31 = Hloc (phase A) then h_in (phase B).
// All exp through __expf (v_exp_f32): scan is VALU-bound (r5: VALUBusy 91%).
// ---------------------------------------------------------------------------
__global__ __launch_bounds__(256) void scan_phaseA(
    const u16* __restrict__ xi,      // bf16 (NTOK, D_INNER)
    const float* __restrict__ dtv,   // fp32 (NTOK, D_INNER)
    const float* __restrict__ proj,  // fp32 (NTOK, 96): B at 64, C at 80
    const float* __restrict__ A_log,
    float* __restrict__ sum)
{
    int c  = blockIdx.x & (SCAN_CH - 1);
    int dg = (blockIdx.x >> 5) & 7;
    int b  = blockIdx.x >> 8;
    int d  = (dg << 8) + threadIdx.x;
    float A[D_STATE], h[D_STATE], P[D_STATE];
    #pragma unroll
    for (int n = 0; n < D_STATE; ++n) {
        A[n] = -__expf(A_log[(size_t)d * D_STATE + n]);
        h[n] = 0.0f;
        P[n] = 1.0f;
    }
    __shared__ float sBC[32][33];
    const float* prow = proj + ((size_t)b * SEQLEN + (size_t)c * SCAN_CL) * 96;
    for (int sub = 0; sub < SCAN_CL / 32; ++sub) {
        __syncthreads();
        {
            int s = threadIdx.x >> 3;
            int k4 = (threadIdx.x & 7) * 4;
            float4 v = *reinterpret_cast<const float4*>(
                prow + (size_t)(sub * 32 + s) * 96 + 64 + k4);
            sBC[s][k4 + 0] = v.x; sBC[s][k4 + 1] = v.y;
            sBC[s][k4 + 2] = v.z; sBC[s][k4 + 3] = v.w;
        }
        __syncthreads();
        for (int s2 = 0; s2 < 32; ++s2) {
            int t = c * SCAN_CL + sub * 32 + s2;
            size_t base = ((size_t)b * SEQLEN + t) * D_INNER + d;
            float xt = b2f(xi[base]);
            float dtt = dtv[base];
            float dbx = dtt * xt;
            #pragma unroll
            for (int n = 0; n < D_STATE; ++n) {
                float dA = __expf(dtt * A[n]);
                h[n] = dA * h[n] + dbx * sBC[s2][n];
                P[n] *= dA;
            }
        }
    }
    size_t sbase = (((size_t)b * SCAN_CH + c) * 32) * D_INNER + d;
    #pragma unroll
    for (int n = 0; n < D_STATE; ++n) {
        sum[sbase + (size_t)n * D_INNER] = P[n];
        sum[sbase + (size_t)(16 + n) * D_INNER] = h[n];
    }
}

__global__ __launch_bounds__(256) void scan_phaseB(float* __restrict__ sum)
{
    int idx = blockIdx.x * 256 + threadIdx.x;   // 8192 total
    int b = idx >> 11;
    int d = idx & (D_INNER - 1);
    float h[D_STATE];
    #pragma unroll
    for (int n = 0; n < D_STATE; ++n) h[n] = 0.0f;
    for (int c = 0; c < SCAN_CH; ++c) {
        size_t sb = (((size_t)b * SCAN_CH + c) * 32) * D_INNER + d;
        #pragma unroll
        for (int n = 0; n < D_STATE; ++n) {
            float P  = sum[sb + (size_t)n * D_INNER];
            float Hl = sum[sb + (size_t)(16 + n) * D_INNER];
            sum[sb + (size_t)(16 + n) * D_INNER] = h[n];   // h_in for chunk c
            h[n] = P * h[n] + Hl;
        }
    }
}

__global__ __launch_bounds__(256) void scan_phaseC(
    const u16* __restrict__ xi,
    const float* __restrict__ dtv,
    const float* __restrict__ proj,
    const float* __restrict__ A_log,
    const float* __restrict__ Dp,
    const u16* __restrict__ z,
    const float* __restrict__ sum,
    u16* __restrict__ yb)            // bf16 gated y out
{
    int c  = blockIdx.x & (SCAN_CH - 1);
    int dg = (blockIdx.x >> 5) & 7;
    int b  = blockIdx.x >> 8;
    int d  = (dg << 8) + threadIdx.x;
    float A[D_STATE], h[D_STATE];
    size_t sbase = (((size_t)b * SCAN_CH + c) * 32) * D_INNER + d;
    #pragma unroll
    for (int n = 0; n < D_STATE; ++n) {
        A[n] = -__expf(A_log[(size_t)d * D_STATE + n]);
        h[n] = sum[sbase + (size_t)(16 + n) * D_INNER];
    }
    float dp = Dp[d];
    __shared__ float sBC[32][33];
    const float* prow = proj + ((size_t)b * SEQLEN + (size_t)c * SCAN_CL) * 96;
    for (int sub = 0; sub < SCAN_CL / 32; ++sub) {
        __syncthreads();
        {
            int s = threadIdx.x >> 3;
            int k4 = (threadIdx.x & 7) * 4;
            float4 v = *reinterpret_cast<const float4*>(
                prow + (size_t)(sub * 32 + s) * 96 + 64 + k4);
            sBC[s][k4 + 0] = v.x; sBC[s][k4 + 1] = v.y;
            sBC[s][k4 + 2] = v.z; sBC[s][k4 + 3] = v.w;
        }
        __syncthreads();
        for (int s2 = 0; s2 < 32; ++s2) {
            int t = c * SCAN_CL + sub * 32 + s2;
            size_t base = ((size_t)b * SEQLEN + t) * D_INNER + d;
            float xt = b2f(xi[base]);
            float dtt = dtv[base];
            float dbx = dtt * xt;
            float yv = 0.0f;
            #pragma unroll
            for (int n = 0; n < D_STATE; ++n) {
                float dA = __expf(dtt * A[n]);
                h[n] = dA * h[n] + dbx * sBC[s2][n];
                yv += h[n] * sBC[s2][D_STATE + n];
            }
            float zv = b2f(z[base]);
            float sz = zv / (1.0f + __expf(-zv));
            yb[base] = bf16r((yv + xt * dp) * sz);
        }
    }
}

// ---------------------------------------------------------------------------
// FF gate: ag = a * gelu(g), bf16 in/out, exact gelu in fp32
// ---------------------------------------------------------------------------
__global__ __launch_bounds__(256) void gelu_gate_kernel(
    const u16* __restrict__ a, const u16* __restrict__ g, u16* __restrict__ o)
{
    int idx = blockIdx.x * 256 + threadIdx.x;
    if (idx >= NTOK * D_INNER / 4) return;
    int e = idx * 4;
    u16x4 av = *reinterpret_cast<const u16x4*>(a + e);
    u16x4 gv = *reinterpret_cast<const u16x4*>(g + e);
    u16x4 ov;
    #pragma unroll
    for (int j = 0; j < 4; ++j) {
        float fa = b2f(av[j]), fg = b2f(gv[j]);
        ov[j] = bf16r(fa * fg * 0.5f * (1.0f + erff(fg * 0.70710678118f)));
    }
    *reinterpret_cast<u16x4*>(o + e) = ov;
}

// ---------------------------------------------------------------------------
extern "C" void kernel_launch(void* const* d_in, const int* in_sizes, int n_in,
                              void* d_out, int out_size, void* d_ws, size_t ws_size,
                              hipStream_t stream)
{
    const float* x       = (const float*)d_in[0];
    const float* rms_w   = (const float*)d_in[1];
    const float* in_w    = (const float*)d_in[2];
    const float* conv_w  = (const float*)d_in[3];
    const float* conv_b  = (const float*)d_in[4];
    const float* xproj_w = (const float*)d_in[5];
    const float* dt_w    = (const float*)d_in[6];
    const float* dt_b    = (const float*)d_in[7];
    const float* A_log   = (const float*)d_in[8];
    const float* Dp      = (const float*)d_in[9];
    const float* out_w   = (const float*)d_in[10];
    const float* ln_w    = (const float*)d_in[11];
    const float* ln_b    = (const float*)d_in[12];
    const float* ff_w1   = (const float*)d_in[13];
    const float* ff_b1   = (const float*)d_in[14];
    const float* ff_w2   = (const float*)d_in[15];
    const float* ff_b2   = (const float*)d_in[16];
    float* out = (float*)d_out;

    // ---- workspace layout (bytes), total ~237 MB ----
    char* p = (char*)d_ws;
    float* P0   = (float*)p;                 // xi_raw f32 -> dt f32 -> ag bf16 overlay
    u16*   agb  = (u16*)p;        p += (size_t)NTOK * D_INNER * 4;   // 64 MB
    u16*   zb   = (u16*)p;                   // z bf16 -> ff_a bf16
    u16*   ffa  = zb;             p += (size_t)NTOK * D_INNER * 2;   // 32 MB
    u16*   ybf  = (u16*)p;                   // y bf16 -> ff_g bf16
    u16*   ffg  = ybf;            p += (size_t)NTOK * D_INNER * 2;   // 32 MB
    u16*   xnb  = (u16*)p;        p += (size_t)NTOK * D_MODEL * 2;   // 16 MB xn/xn2 bf16
    float* proj = (float*)p;      p += (size_t)NTOK * 96 * 4;        //  3 MB
    float* sum  = (float*)p;      p += (size_t)BATCH * SCAN_CH * 32 * D_INNER * 4; // 32 MB
    u16*   xib  = (u16*)p;        p += (size_t)NTOK * D_INNER * 2;   // 32 MB
    u16*   projb= (u16*)p;        p += (size_t)NTOK * 96 * 2;        // 1.5 MB
    u16*   inwT = (u16*)p;        p += (size_t)4096 * 1024 * 2;      //  8 MB
    u16*   xpT  = (u16*)p;        p += (size_t)128 * 2048 * 2;       // 0.5 MB
    u16*   dtwT = (u16*)p;        p += (size_t)2048 * 64 * 2;        // 0.25 MB
    u16*   owT  = (u16*)p;        p += (size_t)1024 * 2048 * 2;      //  4 MB
    u16*   f1T  = (u16*)p;        p += (size_t)4096 * 1024 * 2;      //  8 MB
    u16*   f2T  = (u16*)p;        p += (size_t)1024 * 2048 * 2;      //  4 MB

    // ---- 0. weight transposes (fp32 -> bf16 B^T) ----
    hipLaunchKernelGGL(transpose_w_kernel, dim3(16, 64), dim3(256), 0, stream, in_w,    1024, 4096, inwT);
    hipLaunchKernelGGL(transpose_w_kernel, dim3(32, 2),  dim3(256), 0, stream, xproj_w, 2048,   96, xpT);
    hipLaunchKernelGGL(transpose_w_kernel, dim3(1, 32),  dim3(256), 0, stream, dt_w,      64, 2048, dtwT);
    hipLaunchKernelGGL(transpose_w_kernel, dim3(32, 16), dim3(256), 0, stream, out_w,   2048, 1024, owT);
    hipLaunchKernelGGL(transpose_w_kernel, dim3(16, 64), dim3(256), 0, stream, ff_w1,   1024, 4096, f1T);
    hipLaunchKernelGGL(transpose_w_kernel, dim3(32, 16), dim3(256), 0, stream, ff_w2,   2048, 1024, f2T);

    // ---- 1. RMSNorm -> xn bf16 ----
    hipLaunchKernelGGL(rmsnorm_kernel, dim3(NTOK), dim3(256), 0, stream, x, rms_w, xnb);
    // ---- 2. xi_raw = xn @ in_w[:, :2048] -> P0 (f32) ----
    hipLaunchKernelGGL((gemm_bf16<0>), dim3(16, 64), dim3(256), 0, stream,
                       xnb, D_MODEL, inwT, D_MODEL, D_MODEL, D_INNER,
                       P0, D_INNER, (u16*)nullptr, 0, nullptr, nullptr, 0);
    // ---- 3. z = xn @ in_w[:, 2048:] -> zb (bf16) ----
    hipLaunchKernelGGL((gemm_bf16<1>), dim3(16, 64), dim3(256), 0, stream,
                       xnb, D_MODEL, inwT + (size_t)D_INNER * D_MODEL, D_MODEL, D_MODEL, D_INNER,
                       (float*)nullptr, 0, zb, D_INNER, nullptr, nullptr, 0);
    // ---- 4. xi = silu(conv(xi_raw) + conv_b) -> xib (bf16) ----
    hipLaunchKernelGGL(conv_silu_kernel, dim3((NTOK * D_INNER + 255) / 256), dim3(256), 0, stream,
                       P0, conv_w, conv_b, xib);
    // ---- 5. proj = xi @ xproj_w -> proj f32 + projb bf16 (N=96, padded 128) ----
    hipLaunchKernelGGL((gemm_bf16<2>), dim3(1, 64), dim3(256), 0, stream,
                       xib, D_INNER, xpT, D_INNER, D_INNER, 96,
                       proj, 96, projb, 96, nullptr, nullptr, 0);
    // ---- 6. dt = softplus(proj[:, :64] @ dt_w + dt_b) -> P0 (f32) ----
    hipLaunchKernelGGL((gemm_bf16<3>), dim3(16, 64), dim3(256), 0, stream,
                       projb, 96, dtwT, DT_RANK, DT_RANK, D_INNER,
                       P0, D_INNER, (u16*)nullptr, 0, dt_b, nullptr, 0);
    // ---- 7. chunked scan + fused gate -> ybf (bf16) ----
    hipLaunchKernelGGL(scan_phaseA, dim3(BATCH * 8 * SCAN_CH), dim3(256), 0, stream,
                       xib, P0, proj, A_log, sum);
    hipLaunchKernelGGL(scan_phaseB, dim3(32), dim3(256), 0, stream, sum);
    hipLaunchKernelGGL(scan_phaseC, dim3(BATCH * 8 * SCAN_CH), dim3(256), 0, stream,
                       xib, P0, proj, A_log, Dp, zb, sum, ybf);
    // ---- 8. out = x + y @ out_w ----
    hipLaunchKernelGGL((gemm_bf16<4>), dim3(8, 64), dim3(256), 0, stream,
                       ybf, D_INNER, owT, D_INNER, D_INNER, D_MODEL,
                       out, D_MODEL, (u16*)nullptr, 0, nullptr, x, D_MODEL);
    // ---- 9. LayerNorm -> xn2 bf16 ----
    hipLaunchKernelGGL(layernorm_kernel, dim3(NTOK), dim3(256), 0, stream, out, ln_w, ln_b, xnb);
    // ---- 10/11. ff_a, ff_g = xn2 @ ff_w1 + b1 -> bf16 ----
    hipLaunchKernelGGL((gemm_bf16<5>), dim3(16, 64), dim3(256), 0, stream,
                       xnb, D_MODEL, f1T, D_MODEL, D_MODEL, D_INNER,
                       (float*)nullptr, 0, ffa, D_INNER, ff_b1, nullptr, 0);
    hipLaunchKernelGGL((gemm_bf16<5>), dim3(16, 64), dim3(256), 0, stream,
                       xnb, D_MODEL, f1T + (size_t)D_INNER * D_MODEL, D_MODEL, D_MODEL, D_INNER,
                       (float*)nullptr, 0, ffg, D_INNER, ff_b1 + D_INNER, nullptr, 0);
    // ---- 12. ag = a * gelu(g) -> agb (bf16, overlays P0) ----
    hipLaunchKernelGGL(gelu_gate_kernel, dim3((NTOK * D_INNER / 4 + 255) / 256), dim3(256), 0, stream,
                       ffa, ffg, agb);
    // ---- 13. out += ag @ ff_w2 + ff_b2 ----
    hipLaunchKernelGGL((gemm_bf16<6>), dim3(8, 64), dim3(256), 0, stream,
                       agb, D_INNER, f2T, D_INNER, D_INNER, D_MODEL,
                       out, D_MODEL, (u16*)nullptr, 0, ff_b2, out, D_MODEL);
}

// Round 10
// 812.888 us; speedup vs baseline: 1.3613x; 1.3613x over previous
//
#include <hip/hip_runtime.h>
#include <hip/hip_bf16.h>
#include <cstddef>
#include <cstdint>

#define D_MODEL 1024
#define D_STATE 16
#define D_CONV  4
#define D_INNER 2048
#define DT_RANK 64
#define BATCH   4
#define SEQLEN  2048
#define NTOK    (BATCH * SEQLEN)   // 8192 rows

#define SCAN_CH 32                 // time chunks
#define SCAN_CL 64                 // steps per chunk (SCAN_CH*SCAN_CL == SEQLEN)

typedef unsigned short u16;
typedef __attribute__((ext_vector_type(4))) unsigned short u16x4;
typedef __attribute__((ext_vector_type(8))) short bf16x8;   // 8 bf16 in 4 VGPRs
typedef __attribute__((ext_vector_type(4))) float f32x4;

// bf16 round-to-nearest-even (finite inputs)
__device__ __forceinline__ u16 bf16r(float f) {
    union { float f; uint32_t u; } v; v.f = f;
    uint32_t r = v.u + 0x7FFF + ((v.u >> 16) & 1);
    return (u16)(r >> 16);
}
__device__ __forceinline__ float b2f(u16 u) {
    union { uint32_t u; float f; } v; v.u = ((uint32_t)u) << 16;
    return v.f;
}

// async global->LDS, 16B per lane. LDS base must be wave-uniform; HW scatters lane*16.
__device__ __forceinline__ void gload16(const void* g, void* l) {
    __builtin_amdgcn_global_load_lds(
        (const __attribute__((address_space(1))) uint32_t*)g,
        (__attribute__((address_space(3))) uint32_t*)l, 16, 0, 0);
}

// ---------------------------------------------------------------------------
// Weight transpose + cast: src fp32 [Ksrc][Nsrc] -> dst bf16 [Npad][Ksrc],
// rows n >= Nsrc zero-filled. grid = (Ksrc/64, Npad/64), block 256.
// ---------------------------------------------------------------------------
__global__ __launch_bounds__(256) void transpose_w_kernel(
    const float* __restrict__ src, int Ksrc, int Nsrc, u16* __restrict__ dst)
{
    __shared__ float t[64][65];
    int k0 = blockIdx.x * 64, n0 = blockIdx.y * 64;
    int tid = threadIdx.x;
    #pragma unroll
    for (int i = 0; i < 16; ++i) {
        int idx = tid + i * 256;
        int r = idx >> 6, c = idx & 63;
        float v = 0.0f;
        if (n0 + c < Nsrc) v = src[(size_t)(k0 + r) * Nsrc + (n0 + c)];
        t[r][c] = v;
    }
    __syncthreads();
    #pragma unroll
    for (int i = 0; i < 16; ++i) {
        int idx = tid + i * 256;
        int r = idx >> 6, c = idx & 63;
        dst[(size_t)(n0 + r) * Ksrc + (k0 + c)] = bf16r(t[c][r]);
    }
}

// ---------------------------------------------------------------------------
// RMSNorm: one block per row (1024 floats) -> bf16 out
// ---------------------------------------------------------------------------
__global__ __launch_bounds__(256) void rmsnorm_kernel(
    const float* __restrict__ x, const float* __restrict__ w, u16* __restrict__ o)
{
    int row = blockIdx.x;
    const float* xr = x + (size_t)row * D_MODEL;
    float4 v = *reinterpret_cast<const float4*>(xr + threadIdx.x * 4);
    float ss = v.x * v.x + v.y * v.y + v.z * v.z + v.w * v.w;
    #pragma unroll
    for (int off = 32; off > 0; off >>= 1) ss += __shfl_down(ss, off);
    __shared__ float sred[4];
    if ((threadIdx.x & 63) == 0) sred[threadIdx.x >> 6] = ss;
    __syncthreads();
    float tot = sred[0] + sred[1] + sred[2] + sred[3];
    float scale = rsqrtf(tot * (1.0f / D_MODEL) + 1e-6f);
    float4 wv = *reinterpret_cast<const float4*>(w + threadIdx.x * 4);
    u16x4 ov;
    ov[0] = bf16r(v.x * scale * wv.x); ov[1] = bf16r(v.y * scale * wv.y);
    ov[2] = bf16r(v.z * scale * wv.z); ov[3] = bf16r(v.w * scale * wv.w);
    *reinterpret_cast<u16x4*>(o + (size_t)row * D_MODEL + threadIdx.x * 4) = ov;
}

// ---------------------------------------------------------------------------
// LayerNorm: one block per row -> bf16 out
// ---------------------------------------------------------------------------
__global__ __launch_bounds__(256) void layernorm_kernel(
    const float* __restrict__ x, const float* __restrict__ w, const float* __restrict__ b,
    u16* __restrict__ o)
{
    int row = blockIdx.x;
    const float* xr = x + (size_t)row * D_MODEL;
    float4 v = *reinterpret_cast<const float4*>(xr + threadIdx.x * 4);
    float s1 = v.x + v.y + v.z + v.w;
    float s2 = v.x * v.x + v.y * v.y + v.z * v.z + v.w * v.w;
    #pragma unroll
    for (int off = 32; off > 0; off >>= 1) {
        s1 += __shfl_down(s1, off);
        s2 += __shfl_down(s2, off);
    }
    __shared__ float r1[4], r2[4];
    if ((threadIdx.x & 63) == 0) { r1[threadIdx.x >> 6] = s1; r2[threadIdx.x >> 6] = s2; }
    __syncthreads();
    float t1 = r1[0] + r1[1] + r1[2] + r1[3];
    float t2 = r2[0] + r2[1] + r2[2] + r2[3];
    float mu = t1 * (1.0f / D_MODEL);
    float var = t2 * (1.0f / D_MODEL) - mu * mu;
    float inv = rsqrtf(var + 1e-5f);
    float4 wv = *reinterpret_cast<const float4*>(w + threadIdx.x * 4);
    float4 bv = *reinterpret_cast<const float4*>(b + threadIdx.x * 4);
    u16x4 ov;
    ov[0] = bf16r((v.x - mu) * inv * wv.x + bv.x);
    ov[1] = bf16r((v.y - mu) * inv * wv.y + bv.y);
    ov[2] = bf16r((v.z - mu) * inv * wv.z + bv.z);
    ov[3] = bf16r((v.w - mu) * inv * wv.w + bv.w);
    *reinterpret_cast<u16x4*>(o + (size_t)row * D_MODEL + threadIdx.x * 4) = ov;
}

// ---------------------------------------------------------------------------
// bf16 MFMA GEMM, double-buffered LDS, XCD-swizzled grid.
// C[M,N] = epi(A[M,K]bf16 @ B), B as B^T bf16 [N][ldb]. 128x128 tile, BK=32,
// 256 thr = 4 waves (2x2), wave 64x64 = 4x4 mfma_f32_16x16x32_bf16, f32 acc.
// Split-K via blockIdx.z: this block covers k in [z*K, (z+1)*K).
// EPI: 0 C=f32 | 1 C2=bf16 | 3 softplus(t+bias)->f32 | 4 t+res->f32
//      5 t+bias->bf16 | 6 t+bias+res->f32 | 7 atomicAdd f32
// ---------------------------------------------------------------------------
template<int EPI>
__global__ __launch_bounds__(256) void gemm_bf16(
    const u16* __restrict__ A, int lda,
    const u16* __restrict__ Bt, int ldb,
    int K, int Nreal,
    float* __restrict__ C, int ldc,
    u16* __restrict__ C2, int ldc2,
    const float* __restrict__ bias,
    const float* __restrict__ res, int ldres)
{
    __shared__ u16 As[2][128 * 32];   // [buf][row][k] 64B rows
    __shared__ u16 Bs[2][128 * 32];
    const int tid = threadIdx.x;
    const int l = tid & 63;
    const int w = tid >> 6;
    const int wm = w >> 1, wn = w & 1;

    // bijective XCD swizzle (nwg % 8 == 0 for all our grids)
    int gx = gridDim.x;
    int nwg = gx * gridDim.y;
    int orig = blockIdx.y * gx + blockIdx.x;
    int swz = (orig & 7) * (nwg >> 3) + (orig >> 3);
    const int bm = (swz / gx) * 128, bn = (swz % gx) * 128;
    const int kBeg = blockIdx.z * K;

    f32x4 acc[4][4] = {};

    const char* Ab = (const char*)A + (size_t)bm * lda * 2;
    const char* Bb = (const char*)Bt + (size_t)bn * ldb * 2;
    const int o0 = tid * 16;
    const int row0 = o0 >> 6, col0 = o0 & 63;   // tile row / byte-in-row staging
    const int nIter = K >> 5;

    // stage k-step j into buffer buf
    auto stage = [&](int buf, int j) {
        const int kb = (kBeg + j * 32) * 2;
        u16* AsW = As[buf] + (w << 9);           // wave-uniform base
        u16* BsW = Bs[buf] + (w << 9);
        gload16(Ab + (size_t)row0 * (lda * 2) + kb + col0, AsW);
        gload16(Ab + (size_t)(row0 + 64) * (lda * 2) + kb + col0, AsW + 2048);
        gload16(Bb + (size_t)row0 * (ldb * 2) + kb + col0, BsW);
        gload16(Bb + (size_t)(row0 + 64) * (ldb * 2) + kb + col0, BsW + 2048);
    };

    stage(0, 0);
    __syncthreads();                             // drains vmcnt: buf0 ready

    const int half16 = (l >> 4) << 4;            // k-half byte offset
    for (int j = 0; j < nIter; ++j) {
        const int buf = j & 1;
        if (j + 1 < nIter) stage(buf ^ 1, j + 1);   // prefetch next tile
        bf16x8 af[4], bfr[4];
        #pragma unroll
        for (int m = 0; m < 4; ++m) {
            int r = wm * 64 + m * 16 + (l & 15);
            af[m] = *reinterpret_cast<const bf16x8*>((const char*)As[buf] + r * 64 + half16);
        }
        #pragma unroll
        for (int n = 0; n < 4; ++n) {
            int r = wn * 64 + n * 16 + (l & 15);
            bfr[n] = *reinterpret_cast<const bf16x8*>((const char*)Bs[buf] + r * 64 + half16);
        }
        #pragma unroll
        for (int m = 0; m < 4; ++m)
            #pragma unroll
            for (int n = 0; n < 4; ++n)
                acc[m][n] = __builtin_amdgcn_mfma_f32_16x16x32_bf16(
                    af[m], bfr[n], acc[m][n], 0, 0, 0);
        __syncthreads();   // drains vmcnt (prefetch landed) + all reads done
    }

    const int cr0 = (l >> 4) * 4;
    const int cc = l & 15;
    #pragma unroll
    for (int m = 0; m < 4; ++m) {
        #pragma unroll
        for (int n = 0; n < 4; ++n) {
            #pragma unroll
            for (int r = 0; r < 4; ++r) {
                int row = bm + wm * 64 + m * 16 + cr0 + r;
                int col = bn + wn * 64 + n * 16 + cc;
                if (col >= Nreal) continue;
                float t = acc[m][n][r];
                if (EPI == 3 || EPI == 5 || EPI == 6) t += bias[col];
                if (EPI == 3) t = (t > 20.0f) ? t : __logf(1.0f + __expf(t));
                if (EPI == 4 || EPI == 6) t += res[(size_t)row * ldres + col];
                if (EPI == 0 || EPI == 3 || EPI == 4 || EPI == 6)
                    C[(size_t)row * ldc + col] = t;
                if (EPI == 1 || EPI == 5)
                    C2[(size_t)row * ldc2 + col] = bf16r(t);
                if (EPI == 7)
                    atomicAdd(&C[(size_t)row * ldc + col], t);
            }
        }
    }
}

// ---------------------------------------------------------------------------
// f32 -> bf16 cast (for proj -> projb)
// ---------------------------------------------------------------------------
__global__ __launch_bounds__(256) void cast_bf16_kernel(
    const float* __restrict__ src, u16* __restrict__ dst, int n4)
{
    int idx = blockIdx.x * 256 + threadIdx.x;
    if (idx >= n4) return;
    float4 v = *reinterpret_cast<const float4*>(src + idx * 4);
    u16x4 o;
    o[0] = bf16r(v.x); o[1] = bf16r(v.y); o[2] = bf16r(v.z); o[3] = bf16r(v.w);
    *reinterpret_cast<u16x4*>(dst + idx * 4) = o;
}

// ---------------------------------------------------------------------------
// Depthwise causal conv (width 4) + bias + SiLU. bf16 in -> bf16 out.
// ---------------------------------------------------------------------------
__global__ __launch_bounds__(256) void conv_silu_kernel(
    const u16* __restrict__ xr, const float* __restrict__ cw,
    const float* __restrict__ cb, u16* __restrict__ xi)
{
    int idx = blockIdx.x * 256 + threadIdx.x;
    if (idx >= NTOK * D_INNER) return;
    int d = idx & (D_INNER - 1);
    int bt = idx >> 11;
    int t = bt & (SEQLEN - 1);
    const u16* base = xr + (size_t)bt * D_INNER + d;
    float w0 = cw[d * 4 + 0], w1 = cw[d * 4 + 1], w2 = cw[d * 4 + 2], w3 = cw[d * 4 + 3];
    float acc = cb[d] + w3 * b2f(base[0]);
    if (t >= 1) acc += w2 * b2f(base[-(ptrdiff_t)D_INNER]);
    if (t >= 2) acc += w1 * b2f(base[-(ptrdiff_t)(2 * D_INNER)]);
    if (t >= 3) acc += w0 * b2f(base[-(ptrdiff_t)(3 * D_INNER)]);
    float s = acc / (1.0f + __expf(-acc));
    xi[idx] = bf16r(s);
}

// ---------------------------------------------------------------------------
// Chunked selective scan (3 phases). h_t = dA_t*h_{t-1} + (dt*x)_t*B_t.
// Summary layout: sum[(((b*CH + c)*32 + slot)*D_INNER) + d], slot 0..15 = P
// (per-chunk decay product), 16..31 = Hloc (phase A) then h_in (phase B).
// ---------------------------------------------------------------------------
__global__ __launch_bounds__(256) void scan_phaseA(
    const u16* __restrict__ xi,      // bf16 (NTOK, D_INNER)
    const float* __restrict__ dtv,   // fp32 (NTOK, D_INNER)
    const float* __restrict__ proj,  // fp32 (NTOK, 96): B at 64, C at 80
    const float* __restrict__ A_log,
    float* __restrict__ sum)
{
    int c  = blockIdx.x & (SCAN_CH - 1);
    int dg = (blockIdx.x >> 5) & 7;
    int b  = blockIdx.x >> 8;
    int d  = (dg << 8) + threadIdx.x;
    float A[D_STATE], h[D_STATE], P[D_STATE];
    #pragma unroll
    for (int n = 0; n < D_STATE; ++n) {
        A[n] = -__expf(A_log[(size_t)d * D_STATE + n]);
        h[n] = 0.0f;
        P[n] = 1.0f;
    }
    __shared__ float sBC[32][33];
    const float* prow = proj + ((size_t)b * SEQLEN + (size_t)c * SCAN_CL) * 96;
    for (int sub = 0; sub < SCAN_CL / 32; ++sub) {
        __syncthreads();
        {
            int s = threadIdx.x >> 3;
            int k4 = (threadIdx.x & 7) * 4;
            float4 v = *reinterpret_cast<const float4*>(
                prow + (size_t)(sub * 32 + s) * 96 + 64 + k4);
            sBC[s][k4 + 0] = v.x; sBC[s][k4 + 1] = v.y;
            sBC[s][k4 + 2] = v.z; sBC[s][k4 + 3] = v.w;
        }
        __syncthreads();
        for (int s2 = 0; s2 < 32; ++s2) {
            int t = c * SCAN_CL + sub * 32 + s2;
            size_t base = ((size_t)b * SEQLEN + t) * D_INNER + d;
            float xt = b2f(xi[base]);
            float dtt = dtv[base];
            float dbx = dtt * xt;
            #pragma unroll
            for (int n = 0; n < D_STATE; ++n) {
                float dA = __expf(dtt * A[n]);
                h[n] = dA * h[n] + dbx * sBC[s2][n];
                P[n] *= dA;
            }
        }
    }
    size_t sbase = (((size_t)b * SCAN_CH + c) * 32) * D_INNER + d;
    #pragma unroll
    for (int n = 0; n < D_STATE; ++n) {
        sum[sbase + (size_t)n * D_INNER] = P[n];
        sum[sbase + (size_t)(16 + n) * D_INNER] = h[n];
    }
}

__global__ __launch_bounds__(256) void scan_phaseB(float* __restrict__ sum)
{
    int idx = blockIdx.x * 256 + threadIdx.x;   // 8192 total
    int b = idx >> 11;
    int d = idx & (D_INNER - 1);
    float h[D_STATE];
    #pragma unroll
    for (int n = 0; n < D_STATE; ++n) h[n] = 0.0f;
    for (int c = 0; c < SCAN_CH; ++c) {
        size_t sb = (((size_t)b * SCAN_CH + c) * 32) * D_INNER + d;
        #pragma unroll
        for (int n = 0; n < D_STATE; ++n) {
            float P  = sum[sb + (size_t)n * D_INNER];
            float Hl = sum[sb + (size_t)(16 + n) * D_INNER];
            sum[sb + (size_t)(16 + n) * D_INNER] = h[n];   // h_in for chunk c
            h[n] = P * h[n] + Hl;
        }
    }
}

__global__ __launch_bounds__(256) void scan_phaseC(
    const u16* __restrict__ xi,
    const float* __restrict__ dtv,
    const float* __restrict__ proj,
    const float* __restrict__ A_log,
    const float* __restrict__ Dp,
    const u16* __restrict__ z,
    const float* __restrict__ sum,
    u16* __restrict__ yb)            // bf16 gated y out
{
    int c  = blockIdx.x & (SCAN_CH - 1);
    int dg = (blockIdx.x >> 5) & 7;
    int b  = blockIdx.x >> 8;
    int d  = (dg << 8) + threadIdx.x;
    float A[D_STATE], h[D_STATE];
    size_t sbase = (((size_t)b * SCAN_CH + c) * 32) * D_INNER + d;
    #pragma unroll
    for (int n = 0; n < D_STATE; ++n) {
        A[n] = -__expf(A_log[(size_t)d * D_STATE + n]);
        h[n] = sum[sbase + (size_t)(16 + n) * D_INNER];
    }
    float dp = Dp[d];
    __shared__ float sBC[32][33];
    const float* prow = proj + ((size_t)b * SEQLEN + (size_t)c * SCAN_CL) * 96;
    for (int sub = 0; sub < SCAN_CL / 32; ++sub) {
        __syncthreads();
        {
            int s = threadIdx.x >> 3;
            int k4 = (threadIdx.x & 7) * 4;
            float4 v = *reinterpret_cast<const float4*>(
                prow + (size_t)(sub * 32 + s) * 96 + 64 + k4);
            sBC[s][k4 + 0] = v.x; sBC[s][k4 + 1] = v.y;
            sBC[s][k4 + 2] = v.z; sBC[s][k4 + 3] = v.w;
        }
        __syncthreads();
        for (int s2 = 0; s2 < 32; ++s2) {
            int t = c * SCAN_CL + sub * 32 + s2;
            size_t base = ((size_t)b * SEQLEN + t) * D_INNER + d;
            float xt = b2f(xi[base]);
            float dtt = dtv[base];
            float dbx = dtt * xt;
            float yv = 0.0f;
            #pragma unroll
            for (int n = 0; n < D_STATE; ++n) {
                float dA = __expf(dtt * A[n]);
                h[n] = dA * h[n] + dbx * sBC[s2][n];
                yv += h[n] * sBC[s2][D_STATE + n];
            }
            float zv = b2f(z[base]);
            float sz = zv / (1.0f + __expf(-zv));
            yb[base] = bf16r((yv + xt * dp) * sz);
        }
    }
}

// ---------------------------------------------------------------------------
// FF gate: ag[bt][j] = a * gelu(g) with a = hff[bt][j], g = hff[bt][2048+j]
// ---------------------------------------------------------------------------
__global__ __launch_bounds__(256) void gelu_gate_kernel(
    const u16* __restrict__ hff, u16* __restrict__ o)
{
    int idx = blockIdx.x * 256 + threadIdx.x;
    if (idx >= NTOK * D_INNER / 4) return;
    int e = idx * 4;
    int j = e & (D_INNER - 1);
    int bt = e >> 11;
    const u16* hrow = hff + (size_t)bt * (2 * D_INNER);
    u16x4 av = *reinterpret_cast<const u16x4*>(hrow + j);
    u16x4 gv = *reinterpret_cast<const u16x4*>(hrow + D_INNER + j);
    u16x4 ov;
    #pragma unroll
    for (int k = 0; k < 4; ++k) {
        float fa = b2f(av[k]), fg = b2f(gv[k]);
        ov[k] = bf16r(fa * fg * 0.5f * (1.0f + erff(fg * 0.70710678118f)));
    }
    *reinterpret_cast<u16x4*>(o + (size_t)bt * D_INNER + j) = ov;
}

// ---------------------------------------------------------------------------
extern "C" void kernel_launch(void* const* d_in, const int* in_sizes, int n_in,
                              void* d_out, int out_size, void* d_ws, size_t ws_size,
                              hipStream_t stream)
{
    const float* x       = (const float*)d_in[0];
    const float* rms_w   = (const float*)d_in[1];
    const float* in_w    = (const float*)d_in[2];
    const float* conv_w  = (const float*)d_in[3];
    const float* conv_b  = (const float*)d_in[4];
    const float* xproj_w = (const float*)d_in[5];
    const float* dt_w    = (const float*)d_in[6];
    const float* dt_b    = (const float*)d_in[7];
    const float* A_log   = (const float*)d_in[8];
    const float* Dp      = (const float*)d_in[9];
    const float* out_w   = (const float*)d_in[10];
    const float* ln_w    = (const float*)d_in[11];
    const float* ln_b    = (const float*)d_in[12];
    const float* ff_w1   = (const float*)d_in[13];
    const float* ff_b1   = (const float*)d_in[14];
    const float* ff_w2   = (const float*)d_in[15];
    const float* ff_b2   = (const float*)d_in[16];
    float* out = (float*)d_out;

    // ---- workspace layout (bytes), total ~237 MB, overlays audited ----
    char* p = (char*)d_ws;
    float* P0f  = (float*)p;                 // dt f32 (steps 6-7C)
    u16*   hff  = (u16*)p;        p += (size_t)NTOK * D_INNER * 4;   // 64 MB: hff bf16 [8192][4096] (steps 10-12)
    u16*   zb   = (u16*)p;                   // z bf16 (3-7C)
    u16*   agb  = zb;             p += (size_t)NTOK * D_INNER * 2;   // 32 MB: ag bf16 (12-13)
    u16*   xirb = (u16*)p;                   // xi_raw bf16 (2-4)
    u16*   ybf  = xirb;           p += (size_t)NTOK * D_INNER * 2;   // 32 MB: y bf16 (7C-8)
    u16*   xnb  = (u16*)p;        p += (size_t)NTOK * D_MODEL * 2;   // 16 MB xn/xn2 bf16
    float* proj = (float*)p;      p += (size_t)NTOK * 96 * 4;        //  3 MB
    float* sum  = (float*)p;      p += (size_t)BATCH * SCAN_CH * 32 * D_INNER * 4; // 32 MB
    u16*   xib  = (u16*)p;        p += (size_t)NTOK * D_INNER * 2;   // 32 MB
    u16*   projb= (u16*)p;        p += (size_t)NTOK * 96 * 2;        // 1.5 MB
    u16*   inwT = (u16*)p;        p += (size_t)4096 * 1024 * 2;      //  8 MB
    u16*   xpT  = (u16*)p;        p += (size_t)128 * 2048 * 2;       // 0.5 MB
    u16*   dtwT = (u16*)p;        p += (size_t)2048 * 64 * 2;        // 0.25 MB
    u16*   owT  = (u16*)p;        p += (size_t)1024 * 2048 * 2;      //  4 MB
    u16*   f1T  = (u16*)p;        p += (size_t)4096 * 1024 * 2;      //  8 MB
    u16*   f2T  = (u16*)p;        p += (size_t)1024 * 2048 * 2;      //  4 MB

    // ---- 0. weight transposes (fp32 -> bf16 B^T) ----
    hipLaunchKernelGGL(transpose_w_kernel, dim3(16, 64), dim3(256), 0, stream, in_w,    1024, 4096, inwT);
    hipLaunchKernelGGL(transpose_w_kernel, dim3(32, 2),  dim3(256), 0, stream, xproj_w, 2048,   96, xpT);
    hipLaunchKernelGGL(transpose_w_kernel, dim3(1, 32),  dim3(256), 0, stream, dt_w,      64, 2048, dtwT);
    hipLaunchKernelGGL(transpose_w_kernel, dim3(32, 16), dim3(256), 0, stream, out_w,   2048, 1024, owT);
    hipLaunchKernelGGL(transpose_w_kernel, dim3(16, 64), dim3(256), 0, stream, ff_w1,   1024, 4096, f1T);
    hipLaunchKernelGGL(transpose_w_kernel, dim3(32, 16), dim3(256), 0, stream, ff_w2,   2048, 1024, f2T);

    // ---- 1. RMSNorm -> xn bf16 ----
    hipLaunchKernelGGL(rmsnorm_kernel, dim3(NTOK), dim3(256), 0, stream, x, rms_w, xnb);
    // ---- 2. xi_raw = xn @ in_w[:, :2048] -> xirb (bf16) ----
    hipLaunchKernelGGL((gemm_bf16<1>), dim3(16, 64), dim3(256), 0, stream,
                       xnb, D_MODEL, inwT, D_MODEL, D_MODEL, D_INNER,
                       (float*)nullptr, 0, xirb, D_INNER, nullptr, nullptr, 0);
    // ---- 3. z = xn @ in_w[:, 2048:] -> zb (bf16) ----
    hipLaunchKernelGGL((gemm_bf16<1>), dim3(16, 64), dim3(256), 0, stream,
                       xnb, D_MODEL, inwT + (size_t)D_INNER * D_MODEL, D_MODEL, D_MODEL, D_INNER,
                       (float*)nullptr, 0, zb, D_INNER, nullptr, nullptr, 0);
    // ---- 4. xi = silu(conv(xi_raw) + conv_b) -> xib (bf16) ----
    hipLaunchKernelGGL(conv_silu_kernel, dim3((NTOK * D_INNER + 255) / 256), dim3(256), 0, stream,
                       xirb, conv_w, conv_b, xib);
    // ---- 5. x_proj split-K x8 (atomic f32): proj = xi @ xproj_w ----
    hipMemsetAsync(proj, 0, (size_t)NTOK * 96 * 4, stream);
    hipLaunchKernelGGL((gemm_bf16<7>), dim3(1, 64, 8), dim3(256), 0, stream,
                       xib, D_INNER, xpT, D_INNER, D_INNER / 8, 96,
                       proj, 96, (u16*)nullptr, 0, nullptr, nullptr, 0);
    hipLaunchKernelGGL(cast_bf16_kernel, dim3(NTOK * 96 / 4 / 256), dim3(256), 0, stream,
                       proj, projb, NTOK * 96 / 4);
    // ---- 6. dt = softplus(proj[:, :64] @ dt_w + dt_b) -> P0f (f32) ----
    hipLaunchKernelGGL((gemm_bf16<3>), dim3(16, 64), dim3(256), 0, stream,
                       projb, 96, dtwT, DT_RANK, DT_RANK, D_INNER,
                       P0f, D_INNER, (u16*)nullptr, 0, dt_b, nullptr, 0);
    // ---- 7. chunked scan + fused gate -> ybf (bf16) ----
    hipLaunchKernelGGL(scan_phaseA, dim3(BATCH * 8 * SCAN_CH), dim3(256), 0, stream,
                       xib, P0f, proj, A_log, sum);
    hipLaunchKernelGGL(scan_phaseB, dim3(32), dim3(256), 0, stream, sum);
    hipLaunchKernelGGL(scan_phaseC, dim3(BATCH * 8 * SCAN_CH), dim3(256), 0, stream,
                       xib, P0f, proj, A_log, Dp, zb, sum, ybf);
    // ---- 8. out = x + y @ out_w ----
    hipLaunchKernelGGL((gemm_bf16<4>), dim3(8, 64), dim3(256), 0, stream,
                       ybf, D_INNER, owT, D_INNER, D_INNER, D_MODEL,
                       out, D_MODEL, (u16*)nullptr, 0, nullptr, x, D_MODEL);
    // ---- 9. LayerNorm -> xn2 bf16 ----
    hipLaunchKernelGGL(layernorm_kernel, dim3(NTOK), dim3(256), 0, stream, out, ln_w, ln_b, xnb);
    // ---- 10. ff1 merged: hff = xn2 @ ff_w1 + ff_b1 (N=4096, bf16) ----
    hipLaunchKernelGGL((gemm_bf16<5>), dim3(32, 64), dim3(256), 0, stream,
                       xnb, D_MODEL, f1T, D_MODEL, D_MODEL, 4 * D_MODEL,
                       (float*)nullptr, 0, hff, 4 * D_MODEL, ff_b1, nullptr, 0);
    // ---- 12. ag = a * gelu(g) -> agb (bf16, overlays zb) ----
    hipLaunchKernelGGL(gelu_gate_kernel, dim3((NTOK * D_INNER / 4 + 255) / 256), dim3(256), 0, stream,
                       hff, agb);
    // ---- 13. out += ag @ ff_w2 + ff_b2 ----
    hipLaunchKernelGGL((gemm_bf16<6>), dim3(8, 64), dim3(256), 0, stream,
                       agb, D_INNER, f2T, D_INNER, D_INNER, D_MODEL,
                       out, D_MODEL, (u16*)nullptr, 0, ff_b2, out, D_MODEL);
}